// Round 2
// baseline (505.833 us; speedup 1.0000x reference)
//
#include <hip/hip_runtime.h>
#include <hip/hip_bf16.h>

#define S 2048
#define D 768
#define NH 12
#define HD 64

// ---------- reductions ----------
__device__ __forceinline__ float wave_reduce_sum(float v) {
#pragma unroll
    for (int o = 32; o > 0; o >>= 1) v += __shfl_down(v, o, 64);
    return v;
}
__device__ __forceinline__ float wave_reduce_max(float v) {
#pragma unroll
    for (int o = 32; o > 0; o >>= 1) v = fmaxf(v, __shfl_down(v, o, 64));
    return v;
}

// 256-thread block reductions (4 waves). All threads must call; result broadcast.
__device__ float block_reduce_sum(float v) {
    __shared__ float t4[4];
    int lane = threadIdx.x & 63, wid = threadIdx.x >> 6;
    v = wave_reduce_sum(v);
    __syncthreads();                 // protect t4 from previous use
    if (lane == 0) t4[wid] = v;
    __syncthreads();
    return t4[0] + t4[1] + t4[2] + t4[3];
}
__device__ float block_reduce_max(float v) {
    __shared__ float t4m[4];
    int lane = threadIdx.x & 63, wid = threadIdx.x >> 6;
    v = wave_reduce_max(v);
    __syncthreads();
    if (lane == 0) t4m[wid] = v;
    __syncthreads();
    return fmaxf(fmaxf(t4m[0], t4m[1]), fmaxf(t4m[2], t4m[3]));
}

// ---------- fused residual-add + LayerNorm (one block per row, 256 thr, 3 elem/thr) ----------
__global__ __launch_bounds__(256) void add_ln(const float* __restrict__ A, const float* __restrict__ Bv,
                                              const float* __restrict__ g, const float* __restrict__ be,
                                              float* __restrict__ out) {
    int row = blockIdx.x, t = threadIdx.x;
    const float* a = A + (size_t)row * D;
    const float* b = Bv + (size_t)row * D;
    float x[3];
    float s = 0.f;
#pragma unroll
    for (int i = 0; i < 3; ++i) { int c = t + 256 * i; x[i] = a[c] + b[c]; s += x[i]; }
    float mean = block_reduce_sum(s) * (1.0f / D);
    float vs = 0.f;
#pragma unroll
    for (int i = 0; i < 3; ++i) { float d = x[i] - mean; vs += d * d; }
    float var = block_reduce_sum(vs) * (1.0f / D);
    float rstd = rsqrtf(var + 1e-5f);
#pragma unroll
    for (int i = 0; i < 3; ++i) {
        int c = t + 256 * i;
        out[(size_t)row * D + c] = (x[i] - mean) * rstd * g[c] + be[c];
    }
}

// ---------- generic GEMM: C[M,N] = act(A[M,K] @ B[N,K]^T + bias[N]) ----------
// A,B fp32 row-major (K contiguous for both). 64x64x32 tile, 256 threads (16x16),
// 4x4 outputs/thread. LDS stores transposed [k][m] for conflict-free fragment reads.
#define BM 64
#define BN 64
#define BK 32

template <int RELU>
__global__ __launch_bounds__(256) void gemm_bt(const float* __restrict__ A, const float* __restrict__ B,
                                               const float* __restrict__ bias, float* __restrict__ C,
                                               int M, int N, int K) {
    __shared__ float As[BK][BM + 4];
    __shared__ float Bs[BK][BN + 4];
    int t = threadIdx.x;
    int tx = t & 15, ty = t >> 4;
    int m0 = blockIdx.y * BM, n0 = blockIdx.x * BN;
    float acc[4][4] = {};

    int lr = t >> 3;         // 0..31
    int lk = (t & 7) * 4;    // 0,4,...,28

    for (int k0 = 0; k0 < K; k0 += BK) {
#pragma unroll
        for (int p = 0; p < 2; ++p) {
            int r = lr + 32 * p;
            float4 ua = *reinterpret_cast<const float4*>(A + (size_t)(m0 + r) * K + k0 + lk);
            As[lk + 0][r] = ua.x; As[lk + 1][r] = ua.y;
            As[lk + 2][r] = ua.z; As[lk + 3][r] = ua.w;
            float4 ub = *reinterpret_cast<const float4*>(B + (size_t)(n0 + r) * K + k0 + lk);
            Bs[lk + 0][r] = ub.x; Bs[lk + 1][r] = ub.y;
            Bs[lk + 2][r] = ub.z; Bs[lk + 3][r] = ub.w;
        }
        __syncthreads();
#pragma unroll
        for (int kk = 0; kk < BK; ++kk) {
            float4 av = *reinterpret_cast<const float4*>(&As[kk][ty * 4]);
            float4 bv = *reinterpret_cast<const float4*>(&Bs[kk][tx * 4]);
            float a[4] = {av.x, av.y, av.z, av.w};
            float b[4] = {bv.x, bv.y, bv.z, bv.w};
#pragma unroll
            for (int i = 0; i < 4; ++i)
#pragma unroll
                for (int j = 0; j < 4; ++j)
                    acc[i][j] = fmaf(a[i], b[j], acc[i][j]);
        }
        __syncthreads();
    }

#pragma unroll
    for (int i = 0; i < 4; ++i) {
        int m = m0 + ty * 4 + i;
#pragma unroll
        for (int j = 0; j < 4; ++j) {
            int n = n0 + tx * 4 + j;
            float v = acc[i][j] + bias[n];
            if (RELU) v = fmaxf(v, 0.f);
            C[(size_t)m * N + n] = v;
        }
    }
}

// ---------- sparse masked attention ----------
// One block (256 thr) per query row. Collect adj-nonzero column indices once,
// then per head: scores over ~21 keys -> softmax -> PV.
__global__ __launch_bounds__(256) void attn_sparse(const float* __restrict__ qkv, const int* __restrict__ adj,
                                                   float* __restrict__ O) {
    __shared__ int s_idx[S];     // 8 KB (worst-case capacity; typical n ~ 21)
    __shared__ float s_sc[S];    // 8 KB
    __shared__ float s_q[HD];
    __shared__ int s_cnt;

    int srow = blockIdx.x, t = threadIdx.x;
    if (t == 0) s_cnt = 0;
    __syncthreads();
    for (int j = t; j < S; j += 256)
        if (adj[(size_t)srow * S + j] != 0) { int p = atomicAdd(&s_cnt, 1); s_idx[p] = j; }
    __syncthreads();
    int n = s_cnt;  // >= 1 (diag forced)

    for (int h = 0; h < NH; ++h) {
        if (t < HD) s_q[t] = qkv[(size_t)srow * 3 * D + h * HD + t];
        __syncthreads();

        float lmax = -1e30f;
        for (int i = t; i < n; i += 256) {
            int j = s_idx[i];
            const float4* kp = reinterpret_cast<const float4*>(qkv + (size_t)j * 3 * D + D + h * HD);
            float dot = 0.f;
#pragma unroll
            for (int e4 = 0; e4 < HD / 4; ++e4) {
                float4 u = kp[e4];
                dot += s_q[e4 * 4 + 0] * u.x + s_q[e4 * 4 + 1] * u.y
                     + s_q[e4 * 4 + 2] * u.z + s_q[e4 * 4 + 3] * u.w;
            }
            dot *= 0.125f;  // 1/sqrt(64)
            s_sc[i] = dot;
            lmax = fmaxf(lmax, dot);
        }
        float mx = block_reduce_max(lmax);

        float lsum = 0.f;
        for (int i = t; i < n; i += 256) {
            float p = __expf(s_sc[i] - mx);
            s_sc[i] = p;
            lsum += p;
        }
        float ssum = block_reduce_sum(lsum);   // internal syncthreads also publishes s_sc
        float inv = 1.0f / ssum;

        if (t < HD) {
            float acc = 0.f;
            for (int i = 0; i < n; ++i) {
                int j = s_idx[i];
                acc += s_sc[i] * qkv[(size_t)j * 3 * D + 2 * D + h * HD + t];
            }
            O[(size_t)srow * D + h * HD + t] = acc * inv;
        }
        __syncthreads();  // before next head reuses s_q / s_sc
    }
}

// ---------- launch ----------
extern "C" void kernel_launch(void* const* d_in, const int* in_sizes, int n_in,
                              void* d_out, int out_size, void* d_ws, size_t ws_size,
                              hipStream_t stream) {
    const float* exp_e = (const float*)d_in[0];
    const float* pert  = (const float*)d_in[1];
    const float* w_in  = (const float*)d_in[2];
    const float* b_in  = (const float*)d_in[3];
    const float* w_out = (const float*)d_in[4];
    const float* b_out = (const float*)d_in[5];
    const float* g0  = (const float*)d_in[6];
    const float* be0 = (const float*)d_in[7];
    const float* g1  = (const float*)d_in[8];
    const float* be1 = (const float*)d_in[9];
    const float* g2  = (const float*)d_in[10];
    const float* be2 = (const float*)d_in[11];
    const float* w1  = (const float*)d_in[12];
    const float* b1  = (const float*)d_in[13];
    const float* w2  = (const float*)d_in[14];
    const float* b2  = (const float*)d_in[15];
    const int*   adj = (const int*)d_in[16];
    float* out = (float*)d_out;

    // workspace layout (fp32 elements), with aliasing; total 5*S*D*4 = 31.5 MB
    float* x_in   = (float*)d_ws;                 // [S*D]   live until ln1
    float* qkv    = x_in + (size_t)S * D;         // [S*3D]  live until attention done
    float* attn_o = qkv + (size_t)S * 3 * D;      // [S*D]
    float* proj   = qkv;                          // alias: qkv dead after attn
    float* x1     = qkv + (size_t)S * D;          // alias within old qkv
    float* ffh    = qkv + (size_t)2 * S * D;      // alias within old qkv, [S*D/2]
    float* ffo    = x_in;                         // alias: x_in dead after ln1

    add_ln<<<S, 256, 0, stream>>>(exp_e, pert, g0, be0, x_in);
    gemm_bt<0><<<dim3(3 * D / BN, S / BM), 256, 0, stream>>>(x_in, w_in, b_in, qkv, S, 3 * D, D);
    attn_sparse<<<S, 256, 0, stream>>>(qkv, adj, attn_o);
    gemm_bt<0><<<dim3(D / BN, S / BM), 256, 0, stream>>>(attn_o, w_out, b_out, proj, S, D, D);
    add_ln<<<S, 256, 0, stream>>>(proj, x_in, g1, be1, x1);
    gemm_bt<1><<<dim3((D / 2) / BN, S / BM), 256, 0, stream>>>(x1, w1, b1, ffh, S, D / 2, D);
    gemm_bt<0><<<dim3(D / BN, S / BM), 256, 0, stream>>>(ffh, w2, b2, ffo, S, D, D / 2);
    add_ln<<<S, 256, 0, stream>>>(x1, ffo, g2, be2, out);
}

// Round 3
// 234.048 us; speedup vs baseline: 2.1612x; 2.1612x over previous
//
#include <hip/hip_runtime.h>

#define S 2048
#define D 768
#define NH 12
#define HD 64
#define TD (3 * D)

typedef __bf16 bf16_t;
typedef __bf16 v8bf __attribute__((ext_vector_type(8)));
typedef __bf16 v4bf __attribute__((ext_vector_type(4)));
typedef float v4f __attribute__((ext_vector_type(4)));

__device__ __forceinline__ float toF(float v) { return v; }
__device__ __forceinline__ float toF(bf16_t v) { return (float)v; }

// ---------- reductions (for LN) ----------
__device__ __forceinline__ float wave_reduce_sum(float v) {
#pragma unroll
    for (int o = 32; o > 0; o >>= 1) v += __shfl_down(v, o, 64);
    return v;
}
__device__ float block_reduce_sum(float v) {
    __shared__ float t4[4];
    int lane = threadIdx.x & 63, wid = threadIdx.x >> 6;
    v = wave_reduce_sum(v);
    __syncthreads();
    if (lane == 0) t4[wid] = v;
    __syncthreads();
    return t4[0] + t4[1] + t4[2] + t4[3];
}

// ---------- fused residual-add + LayerNorm ----------
template <typename T1, typename T2, typename TO>
__global__ __launch_bounds__(256) void add_ln(const T1* __restrict__ A, const T2* __restrict__ Bv,
                                              const float* __restrict__ g, const float* __restrict__ be,
                                              TO* __restrict__ out) {
    int row = blockIdx.x, t = threadIdx.x;
    const T1* a = A + (size_t)row * D;
    const T2* b = Bv + (size_t)row * D;
    float x[3];
    float s = 0.f;
#pragma unroll
    for (int i = 0; i < 3; ++i) { int c = t + 256 * i; x[i] = toF(a[c]) + toF(b[c]); s += x[i]; }
    float mean = block_reduce_sum(s) * (1.0f / D);
    float vs = 0.f;
#pragma unroll
    for (int i = 0; i < 3; ++i) { float d = x[i] - mean; vs += d * d; }
    float var = block_reduce_sum(vs) * (1.0f / D);
    float rstd = rsqrtf(var + 1e-5f);
#pragma unroll
    for (int i = 0; i < 3; ++i) {
        int c = t + 256 * i;
        out[(size_t)row * D + c] = (TO)((x[i] - mean) * rstd * g[c] + be[c]);
    }
}

// ---------- fp32 -> bf16 weight conversion ----------
__global__ __launch_bounds__(256) void cvt_bf16(const float* __restrict__ in, bf16_t* __restrict__ out, int n4) {
    int i = blockIdx.x * 256 + threadIdx.x;
    if (i >= n4) return;
    float4 v = ((const float4*)in)[i];
    v4bf o = {(bf16_t)v.x, (bf16_t)v.y, (bf16_t)v.z, (bf16_t)v.w};
    *(v4bf*)(out + (size_t)i * 4) = o;
}

// ---------- MFMA GEMM: C[M,N] = act(A[M,K] @ B[N,K]^T + bias[N]) ----------
// A,B bf16 row-major K-contiguous. 128x128x32 tile, 4 waves, each 64x64 via
// 4x4 grid of 16x16x32 bf16 MFMAs. global_load_lds width-16 staging (no LDS pad).
#define GBM 128
#define GBN 128
#define GBK 32

template <int RELU>
__global__ __launch_bounds__(256) void gemm_mfma(const bf16_t* __restrict__ A, const bf16_t* __restrict__ B,
                                                 const float* __restrict__ bias, bf16_t* __restrict__ C,
                                                 int M, int N, int K) {
    __shared__ bf16_t As[GBM * GBK];  // 8 KB, row-major [m][k], NO padding (global_load_lds)
    __shared__ bf16_t Bs[GBN * GBK];  // 8 KB, row-major [n][k]
    const int t = threadIdx.x;
    const int lane = t & 63, wave = t >> 6;
    const int wm = (wave >> 1) * 64, wn = (wave & 1) * 64;
    const int m0 = blockIdx.y * GBM, n0 = blockIdx.x * GBN;
    const int lm = lane & 15, q = lane >> 4;

    v4f acc[4][4] = {};

    // staging: chunk e = t (rows 0..63) and e = t+256 (rows 64..127); chunk -> 8 bf16
    const bf16_t* Ag0 = A + (size_t)(m0 + (t >> 2)) * K + (t & 3) * 8;
    const bf16_t* Ag1 = Ag0 + (size_t)64 * K;
    const bf16_t* Bg0 = B + (size_t)(n0 + (t >> 2)) * K + (t & 3) * 8;
    const bf16_t* Bg1 = Bg0 + (size_t)64 * K;
    bf16_t* Al0 = As + t * 8;
    bf16_t* Al1 = As + 2048 + t * 8;
    bf16_t* Bl0 = Bs + t * 8;
    bf16_t* Bl1 = Bs + 2048 + t * 8;

    for (int k0 = 0; k0 < K; k0 += GBK) {
        __builtin_amdgcn_global_load_lds((const __attribute__((address_space(1))) void*)(Ag0 + k0),
                                         (__attribute__((address_space(3))) void*)Al0, 16, 0, 0);
        __builtin_amdgcn_global_load_lds((const __attribute__((address_space(1))) void*)(Ag1 + k0),
                                         (__attribute__((address_space(3))) void*)Al1, 16, 0, 0);
        __builtin_amdgcn_global_load_lds((const __attribute__((address_space(1))) void*)(Bg0 + k0),
                                         (__attribute__((address_space(3))) void*)Bl0, 16, 0, 0);
        __builtin_amdgcn_global_load_lds((const __attribute__((address_space(1))) void*)(Bg1 + k0),
                                         (__attribute__((address_space(3))) void*)Bl1, 16, 0, 0);
        __syncthreads();  // drains vmcnt -> staged data visible

        v8bf af[4], bfr[4];
#pragma unroll
        for (int i = 0; i < 4; ++i) {
            af[i]  = *(const v8bf*)(As + (wm + i * 16 + lm) * GBK + q * 8);
            bfr[i] = *(const v8bf*)(Bs + (wn + i * 16 + lm) * GBK + q * 8);
        }
#pragma unroll
        for (int i = 0; i < 4; ++i)
#pragma unroll
            for (int j = 0; j < 4; ++j)
                acc[i][j] = __builtin_amdgcn_mfma_f32_16x16x32_bf16(af[i], bfr[j], acc[i][j], 0, 0, 0);
        __syncthreads();  // protect LDS before next stage
    }

    // D mapping (verified m89/m91): row = quad*4 + reg, col = lane&15
#pragma unroll
    for (int i = 0; i < 4; ++i)
#pragma unroll
        for (int j = 0; j < 4; ++j) {
            int col = n0 + wn + j * 16 + lm;
            float bs = bias[col];
#pragma unroll
            for (int r = 0; r < 4; ++r) {
                int row = m0 + wm + i * 16 + q * 4 + r;
                float v = acc[i][j][r] + bs;
                if (RELU) v = fmaxf(v, 0.f);
                C[(size_t)row * N + col] = (bf16_t)v;
            }
        }
}

// ---------- sparse masked attention (flattened parallelism) ----------
__global__ __launch_bounds__(256) void attn_sparse(const bf16_t* __restrict__ qkv, const int* __restrict__ adj,
                                                   bf16_t* __restrict__ O) {
    __shared__ int s_idx[128];
    __shared__ int s_cnt;
    __shared__ float s_q[D];
    __shared__ float s_p[NH][128];

    const int row = blockIdx.x, t = threadIdx.x;
    const int lane = t & 63, wave = t >> 6;
    if (t == 0) s_cnt = 0;
    __syncthreads();

    // adjacency scan, int4-vectorized (2048 ints / 256 thr = 2 int4 each)
    const int4* arow = (const int4*)(adj + (size_t)row * S);
#pragma unroll
    for (int p = 0; p < 2; ++p) {
        int4 v = arow[t + 256 * p];
        int base = (t + 256 * p) * 4;
        if (v.x) { int k = atomicAdd(&s_cnt, 1); if (k < 128) s_idx[k] = base + 0; }
        if (v.y) { int k = atomicAdd(&s_cnt, 1); if (k < 128) s_idx[k] = base + 1; }
        if (v.z) { int k = atomicAdd(&s_cnt, 1); if (k < 128) s_idx[k] = base + 2; }
        if (v.w) { int k = atomicAdd(&s_cnt, 1); if (k < 128) s_idx[k] = base + 3; }
    }
    // stage Q row (all heads) to LDS as fp32
    for (int c = t; c < D; c += 256) s_q[c] = (float)qkv[(size_t)row * TD + c];
    __syncthreads();
    const int n = (s_cnt < 128) ? s_cnt : 128;  // n ~ 21, >= 1 (diag forced)

    // scores: n*12 items in parallel across 256 threads
    for (int it = t; it < n * NH; it += 256) {
        int i = it / NH, h = it % NH;
        int j = s_idx[i];
        const bf16_t* kp = qkv + (size_t)j * TD + D + h * HD;
        const float* qp = s_q + h * HD;
        float dot = 0.f;
#pragma unroll
        for (int c = 0; c < HD; c += 8) {
            v8bf kv = *(const v8bf*)(kp + c);
#pragma unroll
            for (int e = 0; e < 8; ++e) dot += qp[c + e] * (float)kv[e];
        }
        s_p[h][i] = dot * 0.125f;  // 1/sqrt(64)
    }
    __syncthreads();

    // softmax: 3 heads per wave, shuffle-butterfly over <=128 entries
    for (int h = wave; h < NH; h += 4) {
        float v0 = (lane < n) ? s_p[h][lane] : -1e30f;
        float v1 = (lane + 64 < n) ? s_p[h][lane + 64] : -1e30f;
        float m = fmaxf(v0, v1);
#pragma unroll
        for (int o = 32; o > 0; o >>= 1) m = fmaxf(m, __shfl_xor(m, o, 64));
        float p0 = (lane < n) ? __expf(v0 - m) : 0.f;
        float p1 = (lane + 64 < n) ? __expf(v1 - m) : 0.f;
        float sm = p0 + p1;
#pragma unroll
        for (int o = 32; o > 0; o >>= 1) sm += __shfl_xor(sm, o, 64);
        float inv = 1.f / sm;
        if (lane < n) s_p[h][lane] = p0 * inv;
        if (lane + 64 < n) s_p[h][lane + 64] = p1 * inv;
    }
    __syncthreads();

    // PV: all 768 (h,e) outputs in parallel (3 per thread)
    for (int o = t; o < D; o += 256) {
        int h = o >> 6, e = o & 63;
        const float* pp = s_p[h];
        float acc = 0.f;
        for (int i = 0; i < n; ++i)
            acc += pp[i] * (float)qkv[(size_t)s_idx[i] * TD + 2 * D + h * HD + e];
        O[(size_t)row * D + o] = (bf16_t)acc;
    }
}

// ---------- launch ----------
extern "C" void kernel_launch(void* const* d_in, const int* in_sizes, int n_in,
                              void* d_out, int out_size, void* d_ws, size_t ws_size,
                              hipStream_t stream) {
    const float* exp_e = (const float*)d_in[0];
    const float* pert  = (const float*)d_in[1];
    const float* w_in  = (const float*)d_in[2];
    const float* b_in  = (const float*)d_in[3];
    const float* w_out = (const float*)d_in[4];
    const float* b_out = (const float*)d_in[5];
    const float* g0  = (const float*)d_in[6];
    const float* be0 = (const float*)d_in[7];
    const float* g1  = (const float*)d_in[8];
    const float* be1 = (const float*)d_in[9];
    const float* g2  = (const float*)d_in[10];
    const float* be2 = (const float*)d_in[11];
    const float* w1  = (const float*)d_in[12];
    const float* b1  = (const float*)d_in[13];
    const float* w2  = (const float*)d_in[14];
    const float* b2  = (const float*)d_in[15];
    const int*   adj = (const int*)d_in[16];
    float* out = (float*)d_out;

    const size_t SD = (size_t)S * D;  // 1,572,864
    // bf16 workspace layout (21.6 MB total)
    bf16_t* wb_in  = (bf16_t*)d_ws;               // 2304*768
    bf16_t* wb_out = wb_in + (size_t)TD * D;      // 768*768
    bf16_t* wb_1   = wb_out + (size_t)D * D;      // 384*768
    bf16_t* wb_2   = wb_1 + (size_t)(D / 2) * D;  // 768*384
    bf16_t* x_in   = wb_2 + (size_t)D * (D / 2);  // [S*D]
    bf16_t* qkv    = x_in + SD;                   // [S*3D]
    bf16_t* attn_o = qkv + 3 * SD;                // [S*D]
    bf16_t* proj   = qkv;                         // alias: qkv dead after attn
    bf16_t* x1     = qkv + SD;
    bf16_t* ffh    = qkv + 2 * SD;                // [S*D/2]
    bf16_t* ffo    = attn_o;                      // alias: attn_o dead after out-proj

    cvt_bf16<<<(TD * D / 4 + 255) / 256, 256, 0, stream>>>(w_in, wb_in, TD * D / 4);
    cvt_bf16<<<(D * D / 4 + 255) / 256, 256, 0, stream>>>(w_out, wb_out, D * D / 4);
    cvt_bf16<<<((D / 2) * D / 4 + 255) / 256, 256, 0, stream>>>(w1, wb_1, (D / 2) * D / 4);
    cvt_bf16<<<(D * (D / 2) / 4 + 255) / 256, 256, 0, stream>>>(w2, wb_2, D * (D / 2) / 4);

    add_ln<float, float, bf16_t><<<S, 256, 0, stream>>>(exp_e, pert, g0, be0, x_in);
    gemm_mfma<0><<<dim3(TD / GBN, S / GBM), 256, 0, stream>>>(x_in, wb_in, b_in, qkv, S, TD, D);
    attn_sparse<<<S, 256, 0, stream>>>(qkv, adj, attn_o);
    gemm_mfma<0><<<dim3(D / GBN, S / GBM), 256, 0, stream>>>(attn_o, wb_out, b_out, proj, S, D, D);
    add_ln<bf16_t, bf16_t, bf16_t><<<S, 256, 0, stream>>>(proj, x_in, g1, be1, x1);
    gemm_mfma<1><<<dim3((D / 2) / GBN, S / GBM), 256, 0, stream>>>(x1, wb_1, b1, ffh, S, D / 2, D);
    gemm_mfma<0><<<dim3(D / GBN, S / GBM), 256, 0, stream>>>(ffh, wb_2, b2, ffo, S, D, D / 2);
    add_ln<bf16_t, bf16_t, float><<<S, 256, 0, stream>>>(x1, ffo, g2, be2, out);
}

// Round 4
// 204.249 us; speedup vs baseline: 2.4766x; 1.1459x over previous
//
#include <hip/hip_runtime.h>

#define S 2048
#define D 768
#define NH 12
#define HD 64
#define TD (3 * D)

typedef __bf16 bf16_t;
typedef __bf16 v8bf __attribute__((ext_vector_type(8)));
typedef __bf16 v4bf __attribute__((ext_vector_type(4)));
typedef float v4f __attribute__((ext_vector_type(4)));

__device__ __forceinline__ float toF(float v) { return v; }
__device__ __forceinline__ float toF(bf16_t v) { return (float)v; }

// ---------- reductions ----------
__device__ __forceinline__ float wave_reduce_sum(float v) {
#pragma unroll
    for (int o = 32; o > 0; o >>= 1) v += __shfl_down(v, o, 64);
    return v;
}
__device__ float block_reduce_sum(float v) {
    __shared__ float t4[4];
    int lane = threadIdx.x & 63, wid = threadIdx.x >> 6;
    v = wave_reduce_sum(v);
    __syncthreads();
    if (lane == 0) t4[wid] = v;
    __syncthreads();
    return t4[0] + t4[1] + t4[2] + t4[3];
}

// ---------- fused residual-add + LayerNorm (ln0 only: two fp32 inputs) ----------
__global__ __launch_bounds__(256) void add_ln(const float* __restrict__ A, const float* __restrict__ Bv,
                                              const float* __restrict__ g, const float* __restrict__ be,
                                              bf16_t* __restrict__ out) {
    int row = blockIdx.x, t = threadIdx.x;
    const float* a = A + (size_t)row * D;
    const float* b = Bv + (size_t)row * D;
    float x[3];
    float s = 0.f;
#pragma unroll
    for (int i = 0; i < 3; ++i) { int c = t + 256 * i; x[i] = a[c] + b[c]; s += x[i]; }
    float mean = block_reduce_sum(s) * (1.0f / D);
    float vs = 0.f;
#pragma unroll
    for (int i = 0; i < 3; ++i) { float d = x[i] - mean; vs += d * d; }
    float var = block_reduce_sum(vs) * (1.0f / D);
    float rstd = rsqrtf(var + 1e-5f);
#pragma unroll
    for (int i = 0; i < 3; ++i) {
        int c = t + 256 * i;
        out[(size_t)row * D + c] = (bf16_t)((x[i] - mean) * rstd * g[c] + be[c]);
    }
}

// ---------- single-input LayerNorm (residual already fused into X) ----------
template <typename TO>
__global__ __launch_bounds__(256) void ln_only(const bf16_t* __restrict__ X,
                                               const float* __restrict__ g, const float* __restrict__ be,
                                               TO* __restrict__ out) {
    int row = blockIdx.x, t = threadIdx.x;
    const bf16_t* a = X + (size_t)row * D;
    float x[3];
    float s = 0.f;
#pragma unroll
    for (int i = 0; i < 3; ++i) { int c = t + 256 * i; x[i] = (float)a[c]; s += x[i]; }
    float mean = block_reduce_sum(s) * (1.0f / D);
    float vs = 0.f;
#pragma unroll
    for (int i = 0; i < 3; ++i) { float d = x[i] - mean; vs += d * d; }
    float var = block_reduce_sum(vs) * (1.0f / D);
    float rstd = rsqrtf(var + 1e-5f);
#pragma unroll
    for (int i = 0; i < 3; ++i) {
        int c = t + 256 * i;
        out[(size_t)row * D + c] = (TO)((x[i] - mean) * rstd * g[c] + be[c]);
    }
}

// ---------- fused fp32 -> bf16 conversion of all 4 weight matrices ----------
#define NW0 (TD * D / 4)
#define NW1 (D * D / 4)
#define NW2 ((D / 2) * D / 4)
#define NW3 (D * (D / 2) / 4)
__global__ __launch_bounds__(256) void cvt_all(const float* __restrict__ s0, const float* __restrict__ s1,
                                               const float* __restrict__ s2, const float* __restrict__ s3,
                                               bf16_t* __restrict__ d0, bf16_t* __restrict__ d1,
                                               bf16_t* __restrict__ d2, bf16_t* __restrict__ d3) {
    int i = blockIdx.x * 256 + threadIdx.x;
    const float* sp; bf16_t* dp;
    if (i < NW0) { sp = s0; dp = d0; }
    else if (i < NW0 + NW1) { sp = s1; dp = d1; i -= NW0; }
    else if (i < NW0 + NW1 + NW2) { sp = s2; dp = d2; i -= NW0 + NW1; }
    else if (i < NW0 + NW1 + NW2 + NW3) { sp = s3; dp = d3; i -= NW0 + NW1 + NW2; }
    else return;
    float4 v = ((const float4*)sp)[i];
    v4bf o = {(bf16_t)v.x, (bf16_t)v.y, (bf16_t)v.z, (bf16_t)v.w};
    *(v4bf*)(dp + (size_t)i * 4) = o;
}

// ---------- MFMA GEMM: C[M,N] = act(A[M,K] @ B[N,K]^T + bias[N]) [+ Rsd] ----------
// TM x TN tile, BK=32, 256 threads as 2x2 waves, each wave (TM/2)x(TN/2) via
// 16x16x32 bf16 MFMAs. global_load_lds width-16 staging (LDS layout matches
// wave-lane order: chunk c -> LDS offset c*16B, A/B split at wave boundary).
#define GBK 32

template <int TM, int TN, int RELU, bool RESID>
__global__ __launch_bounds__(256) void gemm_mfma(const bf16_t* __restrict__ A, const bf16_t* __restrict__ B,
                                                 const float* __restrict__ bias,
                                                 const bf16_t* __restrict__ Rsd, bf16_t* __restrict__ C,
                                                 int M, int N, int K) {
    constexpr int CA = TM * 4;              // A chunks (16 B each, 4 per row)
    constexpr int P = (TM + TN) / 64;       // staging chunks per thread
    constexpr int MI = TM / 32, NI = TN / 32;
    __shared__ bf16_t As[TM * GBK];
    __shared__ bf16_t Bs[TN * GBK];
    const int t = threadIdx.x;
    const int lane = t & 63, wave = t >> 6;
    const int wr = (wave >> 1) * (TM / 2), wc = (wave & 1) * (TN / 2);
    const int m0 = blockIdx.y * TM, n0 = blockIdx.x * TN;
    const int lm = lane & 15, q = lane >> 4;

    const bf16_t* gsrc[P];
    bf16_t* ldst[P];
#pragma unroll
    for (int p = 0; p < P; ++p) {
        int c = t + 256 * p;
        if (c < CA) {
            int row = c >> 2, col = (c & 3) * 8;
            gsrc[p] = A + (size_t)(m0 + row) * K + col;
            ldst[p] = As + c * 8;
        } else {
            int cc = c - CA;
            int row = cc >> 2, col = (cc & 3) * 8;
            gsrc[p] = B + (size_t)(n0 + row) * K + col;
            ldst[p] = Bs + cc * 8;
        }
    }

    v4f acc[MI][NI] = {};

    for (int k0 = 0; k0 < K; k0 += GBK) {
#pragma unroll
        for (int p = 0; p < P; ++p)
            __builtin_amdgcn_global_load_lds((const __attribute__((address_space(1))) void*)(gsrc[p] + k0),
                                             (__attribute__((address_space(3))) void*)ldst[p], 16, 0, 0);
        __syncthreads();  // drains vmcnt -> staged data visible

        v8bf af[MI], bfr[NI];
#pragma unroll
        for (int i = 0; i < MI; ++i) af[i] = *(const v8bf*)(As + (wr + i * 16 + lm) * GBK + q * 8);
#pragma unroll
        for (int j = 0; j < NI; ++j) bfr[j] = *(const v8bf*)(Bs + (wc + j * 16 + lm) * GBK + q * 8);
#pragma unroll
        for (int i = 0; i < MI; ++i)
#pragma unroll
            for (int j = 0; j < NI; ++j)
                acc[i][j] = __builtin_amdgcn_mfma_f32_16x16x32_bf16(af[i], bfr[j], acc[i][j], 0, 0, 0);
        __syncthreads();
    }

    // D mapping (verified m89/m91): row = quad*4 + reg, col = lane&15
#pragma unroll
    for (int i = 0; i < MI; ++i)
#pragma unroll
        for (int j = 0; j < NI; ++j) {
            int col = n0 + wc + j * 16 + lm;
            float bs = bias[col];
#pragma unroll
            for (int r = 0; r < 4; ++r) {
                int row = m0 + wr + i * 16 + q * 4 + r;
                float v = acc[i][j][r] + bs;
                if (RELU) v = fmaxf(v, 0.f);
                if (RESID) v += (float)Rsd[(size_t)row * N + col];
                C[(size_t)row * N + col] = (bf16_t)v;
            }
        }
}

// ---------- sparse masked attention (flattened parallelism) ----------
__global__ __launch_bounds__(256) void attn_sparse(const bf16_t* __restrict__ qkv, const int* __restrict__ adj,
                                                   bf16_t* __restrict__ O) {
    __shared__ int s_idx[128];
    __shared__ int s_cnt;
    __shared__ float s_q[D];
    __shared__ float s_p[NH][128];

    const int row = blockIdx.x, t = threadIdx.x;
    const int lane = t & 63, wave = t >> 6;
    if (t == 0) s_cnt = 0;
    __syncthreads();

    const int4* arow = (const int4*)(adj + (size_t)row * S);
#pragma unroll
    for (int p = 0; p < 2; ++p) {
        int4 v = arow[t + 256 * p];
        int base = (t + 256 * p) * 4;
        if (v.x) { int k = atomicAdd(&s_cnt, 1); if (k < 128) s_idx[k] = base + 0; }
        if (v.y) { int k = atomicAdd(&s_cnt, 1); if (k < 128) s_idx[k] = base + 1; }
        if (v.z) { int k = atomicAdd(&s_cnt, 1); if (k < 128) s_idx[k] = base + 2; }
        if (v.w) { int k = atomicAdd(&s_cnt, 1); if (k < 128) s_idx[k] = base + 3; }
    }
    for (int c = t; c < D; c += 256) s_q[c] = (float)qkv[(size_t)row * TD + c];
    __syncthreads();
    const int n = (s_cnt < 128) ? s_cnt : 128;  // n ~ 21, >= 1 (diag forced)

    // scores: n*12 items in parallel
    for (int it = t; it < n * NH; it += 256) {
        int i = it / NH, h = it % NH;
        int j = s_idx[i];
        const bf16_t* kp = qkv + (size_t)j * TD + D + h * HD;
        const float* qp = s_q + h * HD;
        float dot = 0.f;
#pragma unroll
        for (int c = 0; c < HD; c += 8) {
            v8bf kv = *(const v8bf*)(kp + c);
#pragma unroll
            for (int e = 0; e < 8; ++e) dot += qp[c + e] * (float)kv[e];
        }
        s_p[h][i] = dot * 0.125f;  // 1/sqrt(64)
    }
    __syncthreads();

    // softmax: 3 heads per wave
    for (int h = wave; h < NH; h += 4) {
        float v0 = (lane < n) ? s_p[h][lane] : -1e30f;
        float v1 = (lane + 64 < n) ? s_p[h][lane + 64] : -1e30f;
        float m = fmaxf(v0, v1);
#pragma unroll
        for (int o = 32; o > 0; o >>= 1) m = fmaxf(m, __shfl_xor(m, o, 64));
        float p0 = (lane < n) ? __expf(v0 - m) : 0.f;
        float p1 = (lane + 64 < n) ? __expf(v1 - m) : 0.f;
        float sm = p0 + p1;
#pragma unroll
        for (int o = 32; o > 0; o >>= 1) sm += __shfl_xor(sm, o, 64);
        float inv = 1.f / sm;
        if (lane < n) s_p[h][lane] = p0 * inv;
        if (lane + 64 < n) s_p[h][lane + 64] = p1 * inv;
    }
    __syncthreads();

    // PV: all 768 (h,e) outputs in parallel (3 per thread)
    for (int o = t; o < D; o += 256) {
        int h = o >> 6, e = o & 63;
        const float* pp = s_p[h];
        float acc = 0.f;
        for (int i = 0; i < n; ++i)
            acc += pp[i] * (float)qkv[(size_t)s_idx[i] * TD + 2 * D + h * HD + e];
        O[(size_t)row * D + o] = (bf16_t)acc;
    }
}

// ---------- launch ----------
extern "C" void kernel_launch(void* const* d_in, const int* in_sizes, int n_in,
                              void* d_out, int out_size, void* d_ws, size_t ws_size,
                              hipStream_t stream) {
    const float* exp_e = (const float*)d_in[0];
    const float* pert  = (const float*)d_in[1];
    const float* w_in  = (const float*)d_in[2];
    const float* b_in  = (const float*)d_in[3];
    const float* w_out = (const float*)d_in[4];
    const float* b_out = (const float*)d_in[5];
    const float* g0  = (const float*)d_in[6];
    const float* be0 = (const float*)d_in[7];
    const float* g1  = (const float*)d_in[8];
    const float* be1 = (const float*)d_in[9];
    const float* g2  = (const float*)d_in[10];
    const float* be2 = (const float*)d_in[11];
    const float* w1  = (const float*)d_in[12];
    const float* b1  = (const float*)d_in[13];
    const float* w2  = (const float*)d_in[14];
    const float* b2  = (const float*)d_in[15];
    const int*   adj = (const int*)d_in[16];
    float* out = (float*)d_out;

    const size_t SD = (size_t)S * D;
    bf16_t* wb_in  = (bf16_t*)d_ws;               // [2304*768]
    bf16_t* wb_out = wb_in + (size_t)TD * D;      // [768*768]
    bf16_t* wb_1   = wb_out + (size_t)D * D;      // [384*768]
    bf16_t* wb_2   = wb_1 + (size_t)(D / 2) * D;  // [768*384]
    bf16_t* x_in   = wb_2 + (size_t)D * (D / 2);  // [S*D]
    bf16_t* qkv    = x_in + SD;                   // [S*3D]
    bf16_t* attn_o = qkv + 3 * SD;                // [S*D]
    bf16_t* y1     = attn_o + SD;                 // [S*D] pre-LN1 (proj + x_in)
    bf16_t* x1     = y1 + SD;                     // [S*D] ln1 out
    bf16_t* ffh    = x1 + SD;                     // [S*D/2]
    bf16_t* y2     = ffh + SD / 2;                // [S*D] pre-LN2 (ff + x1)

    const int NW = NW0 + NW1 + NW2 + NW3;
    cvt_all<<<(NW + 255) / 256, 256, 0, stream>>>(w_in, w_out, w1, w2, wb_in, wb_out, wb_1, wb_2);
    add_ln<<<S, 256, 0, stream>>>(exp_e, pert, g0, be0, x_in);
    gemm_mfma<64, 128, 0, false><<<dim3(TD / 128, S / 64), 256, 0, stream>>>(x_in, wb_in, b_in, nullptr, qkv, S, TD, D);
    attn_sparse<<<S, 256, 0, stream>>>(qkv, adj, attn_o);
    gemm_mfma<64, 64, 0, true><<<dim3(D / 64, S / 64), 256, 0, stream>>>(attn_o, wb_out, b_out, x_in, y1, S, D, D);
    ln_only<bf16_t><<<S, 256, 0, stream>>>(y1, g1, be1, x1);
    gemm_mfma<64, 64, 1, false><<<dim3((D / 2) / 64, S / 64), 256, 0, stream>>>(x1, wb_1, b1, nullptr, ffh, S, D / 2, D);
    gemm_mfma<64, 64, 0, true><<<dim3(D / 64, S / 64), 256, 0, stream>>>(ffh, wb_2, b2, x1, y2, S, D, D / 2);
    ln_only<float><<<S, 256, 0, stream>>>(y2, g2, be2, out);
}